// Round 6
// baseline (363.414 us; speedup 1.0000x reference)
//
#include <hip/hip_runtime.h>
#include <stdint.h>

// ---------- types ----------
typedef __attribute__((ext_vector_type(8))) _Float16 half8;
typedef __attribute__((ext_vector_type(2))) __fp16   fp16x2;
typedef __attribute__((ext_vector_type(4))) float    f32x4;
typedef __attribute__((ext_vector_type(4))) unsigned short us4;
typedef __attribute__((ext_vector_type(8))) unsigned short us8;

__device__ __forceinline__ unsigned short f2h(float f) {
  union { _Float16 h; unsigned short u; } cv; cv.h = (_Float16)f; return cv.u;
}

// async global->LDS, 16B per lane. lds base wave-uniform; HW adds lane*16.
__device__ __forceinline__ void async_copy16(void* lds, const void* g) {
  __builtin_amdgcn_global_load_lds(
      (__attribute__((address_space(1))) void*)(void*)g,
      (__attribute__((address_space(3))) void*)lds, 16, 0, 0);
}

union U64 { fp16x2 h2[2]; us4 u4; };

// ---------- fused f32 -> f16 conversion (7 regions, 1 launch, 8 elem/thread) ----------
__global__ __launch_bounds__(256) void cvt_all(
    const float* __restrict__ q, const float* __restrict__ k, const float* __restrict__ v,
    const float* __restrict__ wq, const float* __restrict__ wk,
    const float* __restrict__ wv, const float* __restrict__ wo,
    unsigned short* __restrict__ oq, unsigned short* __restrict__ ok,
    unsigned short* __restrict__ ov,
    unsigned short* __restrict__ owq, unsigned short* __restrict__ owk,
    unsigned short* __restrict__ owv, unsigned short* __restrict__ owo) {
  int b = blockIdx.x;
  const float* in; unsigned short* out;
  if      (b < 4096)  { in = q;  out = oq;             }
  else if (b < 8192)  { in = k;  out = ok;  b -= 4096; }
  else if (b < 12288) { in = v;  out = ov;  b -= 8192; }
  else if (b < 12800) { in = wq; out = owq; b -= 12288; }
  else if (b < 13312) { in = wk; out = owk; b -= 12800; }
  else if (b < 13824) { in = wv; out = owv; b -= 13312; }
  else                { in = wo; out = owo; b -= 13824; }
  const int i = (b * 256 + threadIdx.x) * 8;
  const float4 x0 = *(const float4*)(in + i);
  const float4 x1 = *(const float4*)(in + i + 4);
  us8 o;
  o[0] = f2h(x0.x); o[1] = f2h(x0.y); o[2] = f2h(x0.z); o[3] = f2h(x0.w);
  o[4] = f2h(x1.x); o[5] = f2h(x1.y); o[6] = f2h(x1.z); o[7] = f2h(x1.w);
  *(us8*)(out + i) = o;
}

// ---------- 128x128 tile GEMM core: C = A(MxK) * W(NxK)^T, K=1024, BK=32 ----------
// Double-buffered staging, ONE barrier per K-iter: sync (drains prev-iter loads),
// issue next-tile loads, compute current tile. As/Bs are 2 x 8KB buffers.
__device__ __forceinline__ void gemm128_core(const unsigned short* __restrict__ A,
                                             const unsigned short* __restrict__ Bw,
                                             int m0, int n0,
                                             unsigned short* As, unsigned short* Bs,
                                             f32x4 acc[4][4]) {
  const int tid  = threadIdx.x;
  const int w    = tid >> 6;
  const int l15  = tid & 15;
  const int quad = (tid >> 4) & 3;
  const int w0 = w & 1, w1 = w >> 1;
  const f32x4 zero4 = {0.f, 0.f, 0.f, 0.f};
#pragma unroll
  for (int mt = 0; mt < 4; ++mt)
#pragma unroll
    for (int nt = 0; nt < 4; ++nt) acc[mt][nt] = zero4;

  int srcR[2], srcC[2];
#pragma unroll
  for (int c = 0; c < 2; ++c) {
    const int idx = c * 256 + tid;
    srcR[c] = idx >> 2;
    srcC[c] = (idx & 3) ^ (srcR[c] & 3) ^ ((srcR[c] >> 2) & 3);
  }
  const int cs = quad ^ (l15 & 3) ^ (l15 >> 2);

  // preload tile 0 into buffer 0
#pragma unroll
  for (int c = 0; c < 2; ++c) {
    async_copy16((char*)As + c * 4096 + w * 1024, A  + (m0 + srcR[c]) * 1024 + srcC[c] * 8);
    async_copy16((char*)Bs + c * 4096 + w * 1024, Bw + (n0 + srcR[c]) * 1024 + srcC[c] * 8);
  }

  for (int k0 = 0; k0 < 1024; k0 += 32) {
    const int cur = (k0 >> 5) & 1;
    __syncthreads();  // drains tile-k0 loads (in flight during prev compute); frees other buf
    if (k0 < 992) {
      const int nb = cur ^ 1;
#pragma unroll
      for (int c = 0; c < 2; ++c) {
        async_copy16((char*)As + nb * 8192 + c * 4096 + w * 1024,
                     A  + (m0 + srcR[c]) * 1024 + (k0 + 32) + srcC[c] * 8);
        async_copy16((char*)Bs + nb * 8192 + c * 4096 + w * 1024,
                     Bw + (n0 + srcR[c]) * 1024 + (k0 + 32) + srcC[c] * 8);
      }
    }
    const unsigned short* Ac = As + cur * 4096;
    const unsigned short* Bc = Bs + cur * 4096;
    half8 af[4], bf[4];
#pragma unroll
    for (int mt = 0; mt < 4; ++mt)
      af[mt] = *(const half8*)(Ac + (w1 * 64 + mt * 16 + l15) * 32 + cs * 8);
#pragma unroll
    for (int nt = 0; nt < 4; ++nt)
      bf[nt] = *(const half8*)(Bc + (w0 * 64 + nt * 16 + l15) * 32 + cs * 8);
#pragma unroll
    for (int mt = 0; mt < 4; ++mt)
#pragma unroll
      for (int nt = 0; nt < 4; ++nt)
        acc[mt][nt] = __builtin_amdgcn_mfma_f32_16x16x32_f16(af[mt], bf[nt], acc[mt][nt], 0, 0, 0);
  }
}

// ---------- QKV projection; z selects Q/K/V. Q is pre-scaled by 0.125*log2(e). ----------
__global__ __launch_bounds__(256) void gemm_qkv(
    const unsigned short* __restrict__ Xq, const unsigned short* __restrict__ Xk,
    const unsigned short* __restrict__ Xv,
    const unsigned short* __restrict__ Wq, const unsigned short* __restrict__ Wk,
    const unsigned short* __restrict__ Wv,
    const float* __restrict__ bq, const float* __restrict__ bk, const float* __restrict__ bv,
    unsigned short* __restrict__ Qo, unsigned short* __restrict__ Ko,
    unsigned short* __restrict__ Vo) {
  __shared__ __align__(16) unsigned short As[2 * 128 * 32];
  __shared__ __align__(16) unsigned short Bs[2 * 128 * 32];
  const int z = blockIdx.z;
  const unsigned short* A = (z == 0) ? Xq : (z == 1) ? Xk : Xv;
  const unsigned short* W = (z == 0) ? Wq : (z == 1) ? Wk : Wv;
  const float* bias = (z == 0) ? bq : (z == 1) ? bk : bv;
  const int m0 = blockIdx.x * 128, n0 = blockIdx.y * 128;
  f32x4 acc[4][4];
  gemm128_core(A, W, m0, n0, As, Bs, acc);

  const int tid = threadIdx.x;
  const int w = tid >> 6, l15 = tid & 15, quad = (tid >> 4) & 3;
  const int w0 = w & 1, w1 = w >> 1;
  const float qscale = (z == 0) ? 0.18033688011112042f : 1.0f;  // 0.125*log2(e)
#pragma unroll
  for (int mt = 0; mt < 4; ++mt) {
    const int mbase = m0 + w1 * 64 + mt * 16 + quad * 4;  // global row = b*2048+s
    const int bb = mbase >> 11, s = mbase & 2047;
#pragma unroll
    for (int nt = 0; nt < 4; ++nt) {
      const int col = n0 + w0 * 64 + nt * 16 + l15;
      const float badd = bias[col];
      const int h = col >> 6, d = col & 63;
      if (z < 2) {
        unsigned short* dst = (z == 0) ? Qo : Ko;
#pragma unroll
        for (int r = 0; r < 4; ++r)
          dst[((bb * 16 + h) * 2048 + (s + r)) * 64 + d] = f2h((acc[mt][nt][r] + badd) * qscale);
      } else {
        us4 pk;
#pragma unroll
        for (int r = 0; r < 4; ++r) pk[r] = f2h(acc[mt][nt][r] + badd);
        *(us4*)(Vo + ((bb * 16 + h) * 64 + d) * 2048 + s) = pk;
      }
    }
  }
}

// ---------- flash attention, transposed-score orientation, dbuf K/V ----------
// grid (8 qtiles, 64 bh): 256 Q rows/block, 64 rows (4 strips of 16) per wave.
// S^T = K*Q^T so C-layout col = q-row = l15 everywhere; P^T writes are b64,
// P^T reads + V^T A-frags are b128; row sums via ones-A-frag MFMA; no shuffles.
// K/V double-buffered: ONE barrier per iter, loads overlap compute.
#define PKS 72  // P^T key stride (halves): 144B rows -> 16B aligned, bank-clean
__global__ __launch_bounds__(256, 2) void attn_kernel(const unsigned short* __restrict__ Q,
                                                      const unsigned short* __restrict__ K,
                                                      const unsigned short* __restrict__ Vt,
                                                      unsigned short* __restrict__ O) {
  __shared__ __align__(16) unsigned short QP[18432];    // Q staging, then P^T strips
  __shared__ __align__(16) unsigned short Ks[2 * 4096]; // 2 x 8KB
  __shared__ __align__(16) unsigned short Vs[2 * 4096]; // 2 x 8KB, [d][key]
  const int qt = blockIdx.x, bh = blockIdx.y;
  const int tid = threadIdx.x;
  const int w = tid >> 6, l15 = tid & 15, quad = (tid >> 4) & 3;
  const int cq0 = quad ^ (l15 & 7), cq1 = (4 + quad) ^ (l15 & 7);

  // stage Q tile (256 rows x 64), swizzled chunks. dest byte = idx*16.
  const unsigned short* Qg = Q + (bh * 2048 + qt * 256) * 64;
#pragma unroll
  for (int c = 0; c < 8; ++c) {
    const int idx = c * 256 + tid;
    const int r = idx >> 3, cc = (idx & 7) ^ (r & 7);
    async_copy16((char*)QP + c * 4096 + w * 1024, Qg + r * 64 + cc * 8);
  }
  __syncthreads();
  half8 qf[4][2];  // B-frags: B[n=qrow=l15][k=d]
#pragma unroll
  for (int s = 0; s < 4; ++s) {
    const int row = w * 64 + s * 16 + l15;
    qf[s][0] = *(const half8*)(QP + row * 64 + cq0 * 8);
    qf[s][1] = *(const half8*)(QP + row * 64 + cq1 * 8);
  }

  int srcR[2], srcC[2];
#pragma unroll
  for (int c = 0; c < 2; ++c) {
    const int idx = c * 256 + tid;
    srcR[c] = idx >> 3;
    srcC[c] = (idx & 7) ^ (srcR[c] & 7);
  }

  const unsigned short* Kg0 = K + bh * 2048 * 64;
  const unsigned short* Vg0 = Vt + bh * 131072;
  // preload K/V tile 0 into buffer 0
#pragma unroll
  for (int c = 0; c < 2; ++c) {
    async_copy16((char*)Ks + c * 4096 + w * 1024, Kg0 + srcR[c] * 64 + srcC[c] * 8);
    async_copy16((char*)Vs + c * 4096 + w * 1024, Vg0 + srcR[c] * 2048 + srcC[c] * 8);
  }

  const f32x4 zero4 = {0.f, 0.f, 0.f, 0.f};
  f32x4 acc[4][4];   // O^T: acc[strip][dt], rows d=dt*16+quad*4+r, col qrow=l15
  f32x4 lsum[4];
#pragma unroll
  for (int s = 0; s < 4; ++s) {
    lsum[s] = zero4;
#pragma unroll
    for (int dt = 0; dt < 4; ++dt) acc[s][dt] = zero4;
  }
  half8 ones;
#pragma unroll
  for (int i = 0; i < 8; ++i) ones[i] = (_Float16)1.0f;

  unsigned short* Pw = QP + w * 4608;  // 4 strips x 16 x PKS halves, wave-private

  for (int kt = 0; kt < 32; ++kt) {
    const int cur = kt & 1;
    __syncthreads();  // drains tile-kt loads (in flight during prev compute); frees other buf
    if (kt < 31) {
      const int nb = cur ^ 1;
      const unsigned short* Kg = Kg0 + (kt + 1) * 4096;
      const unsigned short* Vg = Vg0 + (kt + 1) * 64;
#pragma unroll
      for (int c = 0; c < 2; ++c) {
        async_copy16((char*)Ks + nb * 8192 + c * 4096 + w * 1024, Kg + srcR[c] * 64 + srcC[c] * 8);
        async_copy16((char*)Vs + nb * 8192 + c * 4096 + w * 1024, Vg + srcR[c] * 2048 + srcC[c] * 8);
      }
    }
    const unsigned short* Kc = Ks + cur * 4096;
    const unsigned short* Vc = Vs + cur * 4096;

    // S^T tile: A = K-frag (m=key), B = Q-frag (n=qrow); exp2 -> P^T (b64 writes)
#pragma unroll
    for (int nt = 0; nt < 4; ++nt) {
      const int rk = nt * 16 + l15;
      half8 ak0 = *(const half8*)(Kc + rk * 64 + cq0 * 8);
      half8 ak1 = *(const half8*)(Kc + rk * 64 + cq1 * 8);
#pragma unroll
      for (int s = 0; s < 4; ++s) {
        f32x4 z = zero4;
        z = __builtin_amdgcn_mfma_f32_16x16x32_f16(ak0, qf[s][0], z, 0, 0, 0);
        z = __builtin_amdgcn_mfma_f32_16x16x32_f16(ak1, qf[s][1], z, 0, 0, 0);
        U64 u;
        u.h2[0] = __builtin_amdgcn_cvt_pkrtz(__builtin_exp2f(z[0]), __builtin_exp2f(z[1]));
        u.h2[1] = __builtin_amdgcn_cvt_pkrtz(__builtin_exp2f(z[2]), __builtin_exp2f(z[3]));
        // keys nt*16+quad*4+r at P^T[strip][qrow=l15][key]
        *(us4*)(Pw + s * 1152 + l15 * PKS + nt * 16 + quad * 4) = u.u4;
      }
    }
    // PV: O^T = V^T * P^T ; l via ones-A-frag MFMA
#pragma unroll
    for (int h = 0; h < 2; ++h) {
      const int ch = h ? cq1 : cq0;
      half8 bp[4];
#pragma unroll
      for (int s = 0; s < 4; ++s) {
        bp[s] = *(const half8*)(Pw + s * 1152 + l15 * PKS + h * 32 + quad * 8);
        lsum[s] = __builtin_amdgcn_mfma_f32_16x16x32_f16(ones, bp[s], lsum[s], 0, 0, 0);
      }
#pragma unroll
      for (int dt = 0; dt < 4; ++dt) {
        half8 av = *(const half8*)(Vc + (dt * 16 + l15) * 64 + ch * 8);
#pragma unroll
        for (int s = 0; s < 4; ++s)
          acc[s][dt] = __builtin_amdgcn_mfma_f32_16x16x32_f16(av, bp[s], acc[s][dt], 0, 0, 0);
      }
    }
  }

  // epilogue: O (B,S,1024) f16; col(l15)=qrow for both acc and lsum -> no shuffles
  const int b = bh >> 4, hd = bh & 15;
#pragma unroll
  for (int s = 0; s < 4; ++s) {
    const float rv = 1.0f / lsum[s][0];
    const int sg = qt * 256 + w * 64 + s * 16 + l15;
    unsigned short* Orow = O + (b * 2048 + sg) * 1024 + hd * 64;
#pragma unroll
    for (int dt = 0; dt < 4; ++dt) {
      U64 u;
      u.h2[0] = __builtin_amdgcn_cvt_pkrtz(acc[s][dt][0] * rv, acc[s][dt][1] * rv);
      u.h2[1] = __builtin_amdgcn_cvt_pkrtz(acc[s][dt][2] * rv, acc[s][dt][3] * rv);
      *(us4*)(Orow + dt * 16 + quad * 4) = u.u4;
    }
  }
}

// ---------- output projection -> f32 ----------
__global__ __launch_bounds__(256) void gemm_out(const unsigned short* __restrict__ A,
                                                const unsigned short* __restrict__ W,
                                                const float* __restrict__ bias,
                                                float* __restrict__ out) {
  __shared__ __align__(16) unsigned short As[2 * 128 * 32];
  __shared__ __align__(16) unsigned short Bs[2 * 128 * 32];
  const int m0 = blockIdx.x * 128, n0 = blockIdx.y * 128;
  f32x4 acc[4][4];
  gemm128_core(A, W, m0, n0, As, Bs, acc);
  const int tid = threadIdx.x;
  const int w = tid >> 6, l15 = tid & 15, quad = (tid >> 4) & 3;
  const int w0 = w & 1, w1 = w >> 1;
#pragma unroll
  for (int mt = 0; mt < 4; ++mt) {
    const int mbase = m0 + w1 * 64 + mt * 16 + quad * 4;
#pragma unroll
    for (int nt = 0; nt < 4; ++nt) {
      const int col = n0 + w0 * 64 + nt * 16 + l15;
      const float badd = bias[col];
#pragma unroll
      for (int r = 0; r < 4; ++r)
        out[(mbase + r) * 1024 + col] = acc[mt][nt][r] + badd;
    }
  }
}

// ---------- launch ----------
extern "C" void kernel_launch(void* const* d_in, const int* in_sizes, int n_in,
                              void* d_out, int out_size, void* d_ws, size_t ws_size,
                              hipStream_t stream) {
  const float* query = (const float*)d_in[0];
  const float* key_  = (const float*)d_in[1];
  const float* value = (const float*)d_in[2];
  const float* Wq = (const float*)d_in[3];
  const float* bq = (const float*)d_in[4];
  const float* Wk = (const float*)d_in[5];
  const float* bk = (const float*)d_in[6];
  const float* Wv = (const float*)d_in[7];
  const float* bv = (const float*)d_in[8];
  const float* Wo = (const float*)d_in[9];
  const float* bo = (const float*)d_in[10];

  unsigned short* ws = (unsigned short*)d_ws;
  unsigned short* xq = ws;               // (B,S,D) f16 of query
  unsigned short* xk = xq + 8388608;
  unsigned short* xv = xk + 8388608;
  unsigned short* wq = xv + 8388608;
  unsigned short* wk = wq + 1048576;
  unsigned short* wv = wk + 1048576;
  unsigned short* wo = wv + 1048576;
  unsigned short* Qw = wo + 1048576;     // (B,H,S,64), pre-scaled by 0.125*log2e
  unsigned short* Kw = Qw + 8388608;     // (B,H,S,64)
  unsigned short* Vw = Kw + 8388608;     // (B,H,64,S) transposed
  unsigned short* Ow = xq;               // reuse query-f16 region for attn output

  cvt_all<<<14336, 256, 0, stream>>>(query, key_, value, Wq, Wk, Wv, Wo,
                                     xq, xk, xv, wq, wk, wv, wo);
  gemm_qkv<<<dim3(64, 8, 3), 256, 0, stream>>>(xq, xk, xv, wq, wk, wv, bq, bk, bv, Qw, Kw, Vw);
  attn_kernel<<<dim3(8, 64), 256, 0, stream>>>(Qw, Kw, Vw, Ow);
  gemm_out<<<dim3(64, 8), 256, 0, stream>>>(Ow, wo, bo, (float*)d_out);
}